// Round 11
// baseline (82.801 us; speedup 1.0000x reference)
//
#include <hip/hip_runtime.h>

typedef __attribute__((ext_vector_type(8))) short short8;
typedef __attribute__((ext_vector_type(4))) short short4v;
typedef __attribute__((ext_vector_type(4))) float f32x4;
typedef __attribute__((ext_vector_type(2))) unsigned int uint2v;

constexpr int SL = 2048, BS = 4, D = 512, H = 8, NH = 64;
constexpr int M_ROWS = SL * BS;   // 8192
constexpr float SCALE = 0.125f;   // 1/sqrt(64)
constexpr float LOG2E = 1.44269504088896340736f;

__device__ __forceinline__ unsigned short f2bf(float f) {
  union { float f; unsigned u; } v; v.f = f;
  unsigned r = v.u + 0x7FFFu + ((v.u >> 16) & 1u);
  return (unsigned short)(r >> 16);
}

__device__ __forceinline__ unsigned cvt_pk_bf16(float a, float b) {
  unsigned r;
  asm("v_cvt_pk_bf16_f32 %0, %1, %2" : "=v"(r) : "v"(a), "v"(b));
  return r;
}

__device__ __forceinline__ float fast_exp2(float x) {
  float r;
  asm("v_exp_f32 %0, %1" : "=v"(r) : "v"(x));
  return r;
}

// async global->LDS, 16B per lane; LDS dest = wave-uniform base + lane*16
__device__ __forceinline__ void gl16(const void* g, void* l) {
  __builtin_amdgcn_global_load_lds(
      (const __attribute__((address_space(1))) unsigned int*)g,
      (__attribute__((address_space(3))) unsigned int*)l, 16, 0, 0);
}

// ---------------------------------------------------------------------------
// prep: W[512][512] f32 row-major -> W^T[n][k] bf16, LDS-tiled 64x64.
// ---------------------------------------------------------------------------
__global__ __launch_bounds__(256) void prep_wt(
    const float* __restrict__ w0, const float* __restrict__ w1,
    const float* __restrict__ w2, const float* __restrict__ w3,
    unsigned short* __restrict__ wtb) {
  __shared__ float tl[64][65];
  const int tid = threadIdx.x;
  const int wi = blockIdx.x >> 6, t6 = blockIdx.x & 63;
  const int k0 = (t6 >> 3) * 64, n0 = (t6 & 7) * 64;
  const float* W = wi == 0 ? w0 : (wi == 1 ? w1 : (wi == 2 ? w2 : w3));
  unsigned short* WT = wtb + (size_t)wi * D * D;

#pragma unroll
  for (int i = 0; i < 4; ++i) {
    int k = (tid >> 4) + i * 16, n4 = (tid & 15) * 4;
    f32x4 v = *reinterpret_cast<const f32x4*>(&W[(size_t)(k0 + k) * D + n0 + n4]);
#pragma unroll
    for (int j = 0; j < 4; ++j) tl[n4 + j][k] = v[j];
  }
  __syncthreads();
#pragma unroll
  for (int i = 0; i < 2; ++i) {
    int n = (tid >> 3) + i * 32, k8 = (tid & 7) * 8;
    union { unsigned u[4]; short8 s; } pk;
#pragma unroll
    for (int j = 0; j < 4; ++j)
      pk.u[j] = cvt_pk_bf16(tl[n][k8 + 2 * j], tl[n][k8 + 2 * j + 1]);
    *reinterpret_cast<short8*>(&WT[(size_t)(n0 + n) * D + k0 + k8]) = pk.s;
  }
}

// ---------------------------------------------------------------------------
// GEMM v2 (unchanged): double-buffered 2-phase pipeline, counted vmcnt,
// XOR-swizzled LDS, V^T epilogue via LDS bounce.
// ---------------------------------------------------------------------------
template <bool A_BF16, int OUT_MODE>
__device__ __forceinline__ void gemm_bt_body(const void* __restrict__ Ap,
                                             const unsigned short* __restrict__ BT,
                                             const float* __restrict__ bias,
                                             void* __restrict__ Outp, float scale,
                                             unsigned short* smem) {
  const int tid = threadIdx.x;
  const int brow = blockIdx.x * 128;
  const int bcol = blockIdx.y * 128;
  const int lane = tid & 63;
  const int wid = tid >> 6;
  const int wr = (wid >> 1) * 64;
  const int wc = (wid & 1) * 64;
  const int r = lane & 15;
  const int g = lane >> 4;

  auto a_buf = [&](int b) { return smem + b * 16384; };
  auto b_buf = [&](int b) { return smem + b * 16384 + 8192; };

  f32x4 acc[4][4];
#pragma unroll
  for (int m = 0; m < 4; ++m)
#pragma unroll
    for (int n = 0; n < 4; ++n) acc[m][n] = f32x4{0.f, 0.f, 0.f, 0.f};

  auto STAGE_B = [&](int kt, int bsel) {
    unsigned short* bl = b_buf(bsel);
#pragma unroll
    for (int j = 0; j < 4; ++j) {
      int c = j * 256 + tid;
      int row = c >> 3, c8 = (c & 7) ^ (row & 7);
      gl16(&BT[(size_t)(bcol + row) * D + kt + c8 * 8], &bl[c * 8]);
    }
  };
  auto STAGE_A_LDS = [&](int kt, int bsel) {
    const unsigned short* A = (const unsigned short*)Ap;
    unsigned short* al = a_buf(bsel);
#pragma unroll
    for (int j = 0; j < 4; ++j) {
      int c = j * 256 + tid;
      int row = c >> 3, c8 = (c & 7) ^ (row & 7);
      gl16(&A[(size_t)(brow + row) * D + kt + c8 * 8], &al[c * 8]);
    }
  };
  auto A_LOAD = [&](int kt, f32x4 (&va)[4][2]) {
    const float* A = (const float*)Ap;
#pragma unroll
    for (int j = 0; j < 4; ++j) {
      int c = j * 256 + tid;
      int row = c >> 3, c8 = (c & 7) ^ (row & 7);
      const float* ap = &A[(size_t)(brow + row) * D + kt + c8 * 8];
      va[j][0] = *reinterpret_cast<const f32x4*>(ap);
      va[j][1] = *reinterpret_cast<const f32x4*>(ap + 4);
    }
  };
  auto A_WRITE = [&](f32x4 (&va)[4][2], int bsel) {
    unsigned short* al = a_buf(bsel);
#pragma unroll
    for (int j = 0; j < 4; ++j) {
      int c = j * 256 + tid;
      union { unsigned u[4]; short8 s; } pk;
      pk.u[0] = cvt_pk_bf16(va[j][0][0], va[j][0][1]);
      pk.u[1] = cvt_pk_bf16(va[j][0][2], va[j][0][3]);
      pk.u[2] = cvt_pk_bf16(va[j][1][0], va[j][1][1]);
      pk.u[3] = cvt_pk_bf16(va[j][1][2], va[j][1][3]);
      *reinterpret_cast<short8*>(&al[c * 8]) = pk.s;
    }
  };
  auto COMPUTE = [&](int bsel) {
    const unsigned short* al = a_buf(bsel);
    const unsigned short* bl = b_buf(bsel);
#pragma unroll
    for (int kk2 = 0; kk2 < 2; ++kk2) {
      short8 af[4], bfr[4];
#pragma unroll
      for (int m = 0; m < 4; ++m)
        af[m] = *reinterpret_cast<const short8*>(
            &al[(wr + m * 16 + r) * 64 + (((kk2 * 4 + g) ^ (r & 7)) * 8)]);
#pragma unroll
      for (int n = 0; n < 4; ++n)
        bfr[n] = *reinterpret_cast<const short8*>(
            &bl[(wc + n * 16 + r) * 64 + (((kk2 * 4 + g) ^ (r & 7)) * 8)]);
      __builtin_amdgcn_s_setprio(1);
#pragma unroll
      for (int m = 0; m < 4; ++m)
#pragma unroll
        for (int n = 0; n < 4; ++n)
          acc[m][n] = __builtin_amdgcn_mfma_f32_16x16x32_bf16(af[m], bfr[n], acc[m][n], 0, 0, 0);
      __builtin_amdgcn_s_setprio(0);
    }
  };

  if (A_BF16) {
    STAGE_A_LDS(0, 0);
    STAGE_B(0, 0);
    asm volatile("s_waitcnt vmcnt(0)" ::: "memory");
  } else {
    f32x4 va[4][2];
    A_LOAD(0, va);
    STAGE_B(0, 0);
    asm volatile("s_waitcnt vmcnt(4)" ::: "memory");
    A_WRITE(va, 0);
    asm volatile("s_waitcnt vmcnt(0) lgkmcnt(0)" ::: "memory");
  }
  __builtin_amdgcn_s_barrier();

#pragma unroll
  for (int t = 0; t < 8; ++t) {
    const int cur = t & 1, nxt = cur ^ 1;
    const int ktn = (t + 1) * 64;
    __builtin_amdgcn_sched_barrier(0);
    f32x4 va[4][2];
    if (t < 7) {
      if (A_BF16) {
        STAGE_A_LDS(ktn, nxt);
        STAGE_B(ktn, nxt);
      } else {
        A_LOAD(ktn, va);
        STAGE_B(ktn, nxt);
      }
    }
    __builtin_amdgcn_sched_barrier(0);
    COMPUTE(cur);
    if (t < 7) {
      if (!A_BF16) {
        asm volatile("s_waitcnt vmcnt(4)" ::: "memory");
        A_WRITE(va, nxt);
      }
      asm volatile("s_waitcnt vmcnt(0) lgkmcnt(0)" ::: "memory");
      __builtin_amdgcn_s_barrier();
    }
  }

  if (OUT_MODE == 2) {
    unsigned short* sc = smem;
    const int wr4 = wr >> 2;
#pragma unroll
    for (int m = 0; m < 4; ++m)
#pragma unroll
      for (int n = 0; n < 4; ++n) {
        int col = wc + n * 16 + r;
        float bv = bias[bcol + col];
        int sl = wr4 + m * 4 + g;
#pragma unroll
        for (int rr = 0; rr < 4; ++rr) {
          int c = (rr * 4 + (sl >> 3)) ^ (col & 7);
          sc[col * 128 + c * 8 + (sl & 7)] = f2bf((acc[m][n][rr] + bv) * scale);
        }
      }
    asm volatile("s_waitcnt lgkmcnt(0)" ::: "memory");
    __builtin_amdgcn_s_barrier();
    unsigned short* VT = (unsigned short*)Outp;
#pragma unroll
    for (int i2 = 0; i2 < 2; ++i2) {
      int q = tid * 2 + i2;
      int col = q >> 2, bb = q & 3;
      int gcol = bcol + col, hh = gcol >> 6, nh = gcol & 63;
      size_t gbase = (((size_t)bb * H + hh) * NH + nh) * SL + (brow >> 2);
#pragma unroll
      for (int j = 0; j < 4; ++j) {
        short8 v = *reinterpret_cast<const short8*>(
            &sc[col * 128 + (((bb * 4 + j) ^ (col & 7)) * 8)]);
        *reinterpret_cast<short8*>(&VT[gbase + j * 8]) = v;
      }
    }
  } else {
#pragma unroll
    for (int m = 0; m < 4; ++m)
#pragma unroll
      for (int n = 0; n < 4; ++n) {
        int gcol = bcol + wc + n * 16 + r;
        float bv = bias[gcol];
#pragma unroll
        for (int rr = 0; rr < 4; ++rr) {
          int grow = brow + wr + m * 16 + g * 4 + rr;
          float val = (acc[m][n][rr] + bv) * scale;
          if (OUT_MODE == 0)
            ((float*)Outp)[(size_t)grow * D + gcol] = val;
          else
            ((unsigned short*)Outp)[(size_t)grow * D + gcol] = f2bf(val);
        }
      }
  }
}

__global__ __launch_bounds__(256, 2) void qkv_gemm(
    const float* __restrict__ x0, const float* __restrict__ x1, const float* __restrict__ x2,
    const unsigned short* __restrict__ wtb,
    const float* __restrict__ b0, const float* __restrict__ b1, const float* __restrict__ b2,
    unsigned short* __restrict__ q_out, unsigned short* __restrict__ k_out,
    unsigned short* __restrict__ vt_out) {
  __shared__ __align__(16) unsigned short smem[2 * 16384];
  int z = blockIdx.z;
  const float* X = z == 0 ? x0 : (z == 1 ? x1 : x2);
  const unsigned short* WT = wtb + (size_t)z * D * D;
  const float* B = z == 0 ? b0 : (z == 1 ? b1 : b2);
  float scale = (z == 0) ? SCALE * LOG2E : 1.0f;
  if (z == 2)
    gemm_bt_body<false, 2>(X, WT, B, vt_out, scale, smem);
  else
    gemm_bt_body<false, 1>(X, WT, B, z == 0 ? q_out : k_out, scale, smem);
}

__global__ __launch_bounds__(256, 2) void gemm_oproj(
    const unsigned short* __restrict__ A, const unsigned short* __restrict__ WT,
    const float* __restrict__ B, float* __restrict__ Outp) {
  __shared__ __align__(16) unsigned short smem[2 * 16384];
  gemm_bt_body<true, 0>(A, WT, B, Outp, 1.0f, smem);
}

// ---------------------------------------------------------------------------
// Flash attention v6: v5 + ZERO-MOVEMENT P->PV.
// The PV contraction order over keys is permuted identically on both operands
// (key sigma(kk,g,j) = kk*32 + (j>>2)*16 + g*4 + (j&3)), which makes the
// B-fragment pf[kk] = {cvt_pk(sv[2kk]), cvt_pk(sv[2kk+1])} purely in-lane:
// no p_lds, no ds_write/ds_read, no lgkmcnt on the P path. V-side reads become
// two b64 LDS loads at (kk*32+g*4)^swz and ^16 (swizzle preserved, 8B align).
// LDS drops 40960 -> 32768 => more blocks/CU. Finalize reuses k_lds after a
// __syncthreads. O aliases Q.
// ---------------------------------------------------------------------------
__global__ __launch_bounds__(256, 4) void flash_attn(
    const unsigned short* __restrict__ Q, const unsigned short* __restrict__ K,
    const unsigned short* __restrict__ Vt, unsigned short* __restrict__ O) {
  __shared__ __align__(16) unsigned short k_lds[2][64 * 64];
  __shared__ __align__(16) unsigned short v_lds[2][64 * 64];

  const int bid = blockIdx.x;
  const int s = bid >> 5, idx = bid & 31;
  const int grp = idx & 7;              // XCD group
  const int bh = grp * 4 + (idx >> 3);  // 4 (b,h) per XCD group
  const int b = bh >> 3, h = bh & 7;
  // balanced slot->qt permutation: each CU's 4 stride-256 slots sum to 62
  const int qt = (s < 8) ? 31 - s : (s < 16) ? s + 8 : (s < 24) ? 31 - s : s - 24;
  const int q0 = qt * 64;

  const int tid = threadIdx.x;
  const int w = tid >> 6, lane = tid & 63;
  const int r = lane & 15, g = lane >> 4;
  const int swz = (r & 7) << 3;         // u16-index XOR (bits 3..5)

  const unsigned short* Qb = Q + (size_t)b * D + h * NH;
  const unsigned short* Kb = K + (size_t)b * D + h * NH;
  const unsigned short* Vb = Vt + ((size_t)(b * H + h) * NH) * SL;
  unsigned short* Ob = O + (size_t)b * D + h * NH;

  auto STAGE = [&](int kt, int bsel) {
    unsigned short* kl = &k_lds[bsel][0];
    unsigned short* vl = &v_lds[bsel][0];
#pragma unroll
    for (int j = 0; j < 2; ++j) {
      int c = j * 256 + tid;
      int row = c >> 3, c8 = (c & 7) ^ (row & 7);
      gl16(&Kb[(size_t)(kt * 64 + row) * (BS * D) + c8 * 8], &kl[c * 8]);
      gl16(&Vb[(size_t)row * SL + kt * 64 + c8 * 8], &vl[c * 8]);
    }
  };

  STAGE(0, 0);

  short8 qf[2];
#pragma unroll
  for (int kk = 0; kk < 2; ++kk)
    qf[kk] = *reinterpret_cast<const short8*>(
        &Qb[(size_t)(q0 + w * 16 + r) * (BS * D) + kk * 32 + g * 8]);

  f32x4 oa[4];
#pragma unroll
  for (int n = 0; n < 4; ++n) oa[n] = f32x4{0.f, 0.f, 0.f, 0.f};
  float mr = -1e30f, lrp = 0.f;   // lrp: per-lane partial denominator

  for (int kt = 0; kt <= qt; ++kt) {
    asm volatile("s_waitcnt vmcnt(0)" ::: "memory");
    __builtin_amdgcn_s_barrier();
    __builtin_amdgcn_sched_barrier(0);
    if (kt + 1 <= qt) STAGE(kt + 1, (kt + 1) & 1);

    const int bsel = kt & 1;
    const unsigned short* kl = &k_lds[bsel][0];
    const unsigned short* vl = &v_lds[bsel][0];
    short8 kf[2][4];
#pragma unroll
    for (int kk = 0; kk < 2; ++kk)
#pragma unroll
      for (int n = 0; n < 4; ++n)
        kf[kk][n] = *reinterpret_cast<const short8*>(
            &kl[(n * 16 + r) * 64 + ((kk * 32 + g * 8) ^ swz)]);

    f32x4 sv[4];
#pragma unroll
    for (int n = 0; n < 4; ++n) sv[n] = f32x4{0.f, 0.f, 0.f, 0.f};
#pragma unroll
    for (int kk = 0; kk < 2; ++kk) {
      __builtin_amdgcn_s_setprio(1);
#pragma unroll
      for (int n = 0; n < 4; ++n)
        sv[n] = __builtin_amdgcn_mfma_f32_16x16x32_bf16(kf[kk][n], qf[kk], sv[n], 0, 0, 0);
      __builtin_amdgcn_s_setprio(0);
    }

    // V^T fragments, sigma-permuted key order: two b64 reads per (kk,n)
    short8 vt[2][4];
#pragma unroll
    for (int kk = 0; kk < 2; ++kk)
#pragma unroll
      for (int n = 0; n < 4; ++n) {
        int base = (kk * 32 + g * 4) ^ swz;
        union { short4v h[2]; short8 s8; } u;
        u.h[0] = *reinterpret_cast<const short4v*>(&vl[(n * 16 + r) * 64 + base]);
        u.h[1] = *reinterpret_cast<const short4v*>(&vl[(n * 16 + r) * 64 + (base ^ 16)]);
        vt[kk][n] = u.s8;
      }

    if (kt == qt) {
      int qrow = q0 + w * 16 + r;
#pragma unroll
      for (int n = 0; n < 4; ++n)
#pragma unroll
        for (int rr = 0; rr < 4; ++rr)
          if (kt * 64 + n * 16 + g * 4 + rr > qrow) sv[n][rr] = -1e30f;
    }

    // in-lane max (tree) -> lazy cross-lane reduce
    float t0 = fmaxf(fmaxf(sv[0][0], sv[0][1]), sv[0][2]);
    float t1 = fmaxf(fmaxf(sv[0][3], sv[1][0]), sv[1][1]);
    float t2 = fmaxf(fmaxf(sv[1][2], sv[1][3]), sv[2][0]);
    float t3 = fmaxf(fmaxf(sv[2][1], sv[2][2]), sv[2][3]);
    float t4 = fmaxf(fmaxf(sv[3][0], sv[3][1]), sv[3][2]);
    float mxl = fmaxf(fmaxf(fmaxf(t0, t1), fmaxf(t2, t3)), fmaxf(t4, sv[3][3]));
    bool need = __any(mxl > mr + 8.f);
    float mold = mr;
    float mnew = mold;
    if (need) {
      float mx = fmaxf(mxl, __shfl_xor(mxl, 16));
      mx = fmaxf(mx, __shfl_xor(mx, 32));
      mnew = fmaxf(mold, mx);
    }
#pragma unroll
    for (int n = 0; n < 4; ++n)
#pragma unroll
      for (int rr = 0; rr < 4; ++rr)
        sv[n][rr] = fast_exp2(sv[n][rr] - mnew);
    float a0 = (sv[0][0] + sv[0][1]) + (sv[0][2] + sv[0][3]);
    float a1 = (sv[1][0] + sv[1][1]) + (sv[1][2] + sv[1][3]);
    float a2 = (sv[2][0] + sv[2][1]) + (sv[2][2] + sv[2][3]);
    float a3 = (sv[3][0] + sv[3][1]) + (sv[3][2] + sv[3][3]);
    float psl = (a0 + a1) + (a2 + a3);
    if (need) {
      float sf = fast_exp2(mold - mnew);
      mr = mnew;
      lrp = lrp * sf + psl;
#pragma unroll
      for (int n = 0; n < 4; ++n) oa[n] *= sf;
    } else {
      lrp += psl;
    }

    // P fragments: purely in-lane under sigma (no LDS, no shuffles)
    short8 pf[2];
#pragma unroll
    for (int kk = 0; kk < 2; ++kk) {
      union { unsigned u[4]; short8 s8; } P;
      P.u[0] = cvt_pk_bf16(sv[2 * kk][0], sv[2 * kk][1]);
      P.u[1] = cvt_pk_bf16(sv[2 * kk][2], sv[2 * kk][3]);
      P.u[2] = cvt_pk_bf16(sv[2 * kk + 1][0], sv[2 * kk + 1][1]);
      P.u[3] = cvt_pk_bf16(sv[2 * kk + 1][2], sv[2 * kk + 1][3]);
      pf[kk] = P.s8;
    }

#pragma unroll
    for (int kk = 0; kk < 2; ++kk) {
      __builtin_amdgcn_s_setprio(1);
#pragma unroll
      for (int n = 0; n < 4; ++n)
        oa[n] = __builtin_amdgcn_mfma_f32_16x16x32_bf16(vt[kk][n], pf[kk], oa[n], 0, 0, 0);
      __builtin_amdgcn_s_setprio(0);
    }
  }

  // finalize: reduce lrp once, normalize, transpose via (now-free) k_lds slice
  __syncthreads();
  {
    unsigned short* pw = &k_lds[0][0] + w * 2048;
    float lr = lrp + __shfl_xor(lrp, 16);
    lr += __shfl_xor(lr, 32);
    float inv = 1.0f / lr;
#pragma unroll
    for (int n = 0; n < 4; ++n) {
      uint2v pk;
      pk.x = cvt_pk_bf16(oa[n][0] * inv, oa[n][1] * inv);
      pk.y = cvt_pk_bf16(oa[n][2] * inv, oa[n][3] * inv);
      *reinterpret_cast<uint2v*>(&pw[r * 64 + ((n * 16 + g * 4) ^ swz)]) = pk;
    }
    asm volatile("s_waitcnt lgkmcnt(0)" ::: "memory");
    __builtin_amdgcn_sched_barrier(0);
#pragma unroll
    for (int i2 = 0; i2 < 2; ++i2) {
      int c = i2 * 64 + lane;
      int row = c >> 3, c8 = c & 7;
      short8 v = *reinterpret_cast<const short8*>(&pw[row * 64 + c8 * 8]);
      *reinterpret_cast<short8*>(
          &Ob[(size_t)(q0 + w * 16 + row) * (BS * D) + ((c8 ^ (row & 7)) * 8)]) = v;
    }
  }
}

// ---------------------------------------------------------------------------
extern "C" void kernel_launch(void* const* d_in, const int* in_sizes, int n_in,
                              void* d_out, int out_size, void* d_ws, size_t ws_size,
                              hipStream_t stream) {
  const float* x  = (const float*)d_in[0];
  const float* kx = (const float*)d_in[1];
  const float* vx = (const float*)d_in[2];
  const float* Wq = (const float*)d_in[3];
  const float* bq = (const float*)d_in[4];
  const float* Wk = (const float*)d_in[5];
  const float* bk = (const float*)d_in[6];
  const float* Wv = (const float*)d_in[7];
  const float* bv = (const float*)d_in[8];
  const float* Wo = (const float*)d_in[9];
  const float* bo = (const float*)d_in[10];

  // workspace (bf16), 26 MB: qb (attn-out aliases) | kb | vtb | wtb (2 MB)
  unsigned short* ws = (unsigned short*)d_ws;
  unsigned short* qb  = ws;
  unsigned short* kb  = ws + (size_t)M_ROWS * D;
  unsigned short* vtb = ws + (size_t)M_ROWS * D * 2;
  unsigned short* wtb = ws + (size_t)M_ROWS * D * 3;

  prep_wt<<<dim3(256), dim3(256), 0, stream>>>(Wq, Wk, Wv, Wo, wtb);
  qkv_gemm<<<dim3(64, 4, 3), dim3(256), 0, stream>>>(x, kx, vx, wtb, bq, bk, bv,
                                                     qb, kb, vtb);
  flash_attn<<<dim3(1024), dim3(256), 0, stream>>>(qb, kb, vtb, qb);
  gemm_oproj<<<dim3(64, 4, 1), dim3(256), 0, stream>>>(qb, wtb + (size_t)3 * D * D,
                                                       bo, (float*)d_out);
}

// Round 12
// 77.034 us; speedup vs baseline: 1.0749x; 1.0749x over previous
//
#include <hip/hip_runtime.h>

typedef __attribute__((ext_vector_type(8))) short short8;
typedef __attribute__((ext_vector_type(4))) short short4v;
typedef __attribute__((ext_vector_type(4))) float f32x4;
typedef __attribute__((ext_vector_type(2))) unsigned int uint2v;

constexpr int SL = 2048, BS = 4, D = 512, H = 8, NH = 64;
constexpr int M_ROWS = SL * BS;   // 8192
constexpr float SCALE = 0.125f;   // 1/sqrt(64)
constexpr float LOG2E = 1.44269504088896340736f;

__device__ __forceinline__ unsigned short f2bf(float f) {
  union { float f; unsigned u; } v; v.f = f;
  unsigned r = v.u + 0x7FFFu + ((v.u >> 16) & 1u);
  return (unsigned short)(r >> 16);
}

__device__ __forceinline__ unsigned cvt_pk_bf16(float a, float b) {
  unsigned r;
  asm("v_cvt_pk_bf16_f32 %0, %1, %2" : "=v"(r) : "v"(a), "v"(b));
  return r;
}

__device__ __forceinline__ float fast_exp2(float x) {
  float r;
  asm("v_exp_f32 %0, %1" : "=v"(r) : "v"(x));
  return r;
}

// async global->LDS, 16B per lane; LDS dest = wave-uniform base + lane*16
__device__ __forceinline__ void gl16(const void* g, void* l) {
  __builtin_amdgcn_global_load_lds(
      (const __attribute__((address_space(1))) unsigned int*)g,
      (__attribute__((address_space(3))) unsigned int*)l, 16, 0, 0);
}

// ---------------------------------------------------------------------------
// prep: W[512][512] f32 row-major -> W^T[n][k] bf16, LDS-tiled 64x64.
// ---------------------------------------------------------------------------
__global__ __launch_bounds__(256) void prep_wt(
    const float* __restrict__ w0, const float* __restrict__ w1,
    const float* __restrict__ w2, const float* __restrict__ w3,
    unsigned short* __restrict__ wtb) {
  __shared__ float tl[64][65];
  const int tid = threadIdx.x;
  const int wi = blockIdx.x >> 6, t6 = blockIdx.x & 63;
  const int k0 = (t6 >> 3) * 64, n0 = (t6 & 7) * 64;
  const float* W = wi == 0 ? w0 : (wi == 1 ? w1 : (wi == 2 ? w2 : w3));
  unsigned short* WT = wtb + (size_t)wi * D * D;

#pragma unroll
  for (int i = 0; i < 4; ++i) {
    int k = (tid >> 4) + i * 16, n4 = (tid & 15) * 4;
    f32x4 v = *reinterpret_cast<const f32x4*>(&W[(size_t)(k0 + k) * D + n0 + n4]);
#pragma unroll
    for (int j = 0; j < 4; ++j) tl[n4 + j][k] = v[j];
  }
  __syncthreads();
#pragma unroll
  for (int i = 0; i < 2; ++i) {
    int n = (tid >> 3) + i * 32, k8 = (tid & 7) * 8;
    union { unsigned u[4]; short8 s; } pk;
#pragma unroll
    for (int j = 0; j < 4; ++j)
      pk.u[j] = cvt_pk_bf16(tl[n][k8 + 2 * j], tl[n][k8 + 2 * j + 1]);
    *reinterpret_cast<short8*>(&WT[(size_t)(n0 + n) * D + k0 + k8]) = pk.s;
  }
}

// ---------------------------------------------------------------------------
// GEMM v2: double-buffered 2-phase pipeline, counted vmcnt, XOR-swizzled LDS.
// OUT_MODE 2 (V^T) now also applies the per-64-key sigma permutation
// perm5(sl) = ((sl>>2)&3)*8 + ((sl>>4)&1)*4 + (sl&3) inside the LDS bounce,
// so flash's PV B-fragment is purely in-lane with single-b128 V reads.
// ---------------------------------------------------------------------------
template <bool A_BF16, int OUT_MODE>
__device__ __forceinline__ void gemm_bt_body(const void* __restrict__ Ap,
                                             const unsigned short* __restrict__ BT,
                                             const float* __restrict__ bias,
                                             void* __restrict__ Outp, float scale,
                                             unsigned short* smem) {
  const int tid = threadIdx.x;
  const int brow = blockIdx.x * 128;
  const int bcol = blockIdx.y * 128;
  const int lane = tid & 63;
  const int wid = tid >> 6;
  const int wr = (wid >> 1) * 64;
  const int wc = (wid & 1) * 64;
  const int r = lane & 15;
  const int g = lane >> 4;

  auto a_buf = [&](int b) { return smem + b * 16384; };
  auto b_buf = [&](int b) { return smem + b * 16384 + 8192; };

  f32x4 acc[4][4];
#pragma unroll
  for (int m = 0; m < 4; ++m)
#pragma unroll
    for (int n = 0; n < 4; ++n) acc[m][n] = f32x4{0.f, 0.f, 0.f, 0.f};

  auto STAGE_B = [&](int kt, int bsel) {
    unsigned short* bl = b_buf(bsel);
#pragma unroll
    for (int j = 0; j < 4; ++j) {
      int c = j * 256 + tid;
      int row = c >> 3, c8 = (c & 7) ^ (row & 7);
      gl16(&BT[(size_t)(bcol + row) * D + kt + c8 * 8], &bl[c * 8]);
    }
  };
  auto STAGE_A_LDS = [&](int kt, int bsel) {
    const unsigned short* A = (const unsigned short*)Ap;
    unsigned short* al = a_buf(bsel);
#pragma unroll
    for (int j = 0; j < 4; ++j) {
      int c = j * 256 + tid;
      int row = c >> 3, c8 = (c & 7) ^ (row & 7);
      gl16(&A[(size_t)(brow + row) * D + kt + c8 * 8], &al[c * 8]);
    }
  };
  auto A_LOAD = [&](int kt, f32x4 (&va)[4][2]) {
    const float* A = (const float*)Ap;
#pragma unroll
    for (int j = 0; j < 4; ++j) {
      int c = j * 256 + tid;
      int row = c >> 3, c8 = (c & 7) ^ (row & 7);
      const float* ap = &A[(size_t)(brow + row) * D + kt + c8 * 8];
      va[j][0] = *reinterpret_cast<const f32x4*>(ap);
      va[j][1] = *reinterpret_cast<const f32x4*>(ap + 4);
    }
  };
  auto A_WRITE = [&](f32x4 (&va)[4][2], int bsel) {
    unsigned short* al = a_buf(bsel);
#pragma unroll
    for (int j = 0; j < 4; ++j) {
      int c = j * 256 + tid;
      union { unsigned u[4]; short8 s; } pk;
      pk.u[0] = cvt_pk_bf16(va[j][0][0], va[j][0][1]);
      pk.u[1] = cvt_pk_bf16(va[j][0][2], va[j][0][3]);
      pk.u[2] = cvt_pk_bf16(va[j][1][0], va[j][1][1]);
      pk.u[3] = cvt_pk_bf16(va[j][1][2], va[j][1][3]);
      *reinterpret_cast<short8*>(&al[c * 8]) = pk.s;
    }
  };
  auto COMPUTE = [&](int bsel) {
    const unsigned short* al = a_buf(bsel);
    const unsigned short* bl = b_buf(bsel);
#pragma unroll
    for (int kk2 = 0; kk2 < 2; ++kk2) {
      short8 af[4], bfr[4];
#pragma unroll
      for (int m = 0; m < 4; ++m)
        af[m] = *reinterpret_cast<const short8*>(
            &al[(wr + m * 16 + r) * 64 + (((kk2 * 4 + g) ^ (r & 7)) * 8)]);
#pragma unroll
      for (int n = 0; n < 4; ++n)
        bfr[n] = *reinterpret_cast<const short8*>(
            &bl[(wc + n * 16 + r) * 64 + (((kk2 * 4 + g) ^ (r & 7)) * 8)]);
      __builtin_amdgcn_s_setprio(1);
#pragma unroll
      for (int m = 0; m < 4; ++m)
#pragma unroll
        for (int n = 0; n < 4; ++n)
          acc[m][n] = __builtin_amdgcn_mfma_f32_16x16x32_bf16(af[m], bfr[n], acc[m][n], 0, 0, 0);
      __builtin_amdgcn_s_setprio(0);
    }
  };

  if (A_BF16) {
    STAGE_A_LDS(0, 0);
    STAGE_B(0, 0);
    asm volatile("s_waitcnt vmcnt(0)" ::: "memory");
  } else {
    f32x4 va[4][2];
    A_LOAD(0, va);
    STAGE_B(0, 0);
    asm volatile("s_waitcnt vmcnt(4)" ::: "memory");
    A_WRITE(va, 0);
    asm volatile("s_waitcnt vmcnt(0) lgkmcnt(0)" ::: "memory");
  }
  __builtin_amdgcn_s_barrier();

#pragma unroll
  for (int t = 0; t < 8; ++t) {
    const int cur = t & 1, nxt = cur ^ 1;
    const int ktn = (t + 1) * 64;
    __builtin_amdgcn_sched_barrier(0);
    f32x4 va[4][2];
    if (t < 7) {
      if (A_BF16) {
        STAGE_A_LDS(ktn, nxt);
        STAGE_B(ktn, nxt);
      } else {
        A_LOAD(ktn, va);
        STAGE_B(ktn, nxt);
      }
    }
    __builtin_amdgcn_sched_barrier(0);
    COMPUTE(cur);
    if (t < 7) {
      if (!A_BF16) {
        asm volatile("s_waitcnt vmcnt(4)" ::: "memory");
        A_WRITE(va, nxt);
      }
      asm volatile("s_waitcnt vmcnt(0) lgkmcnt(0)" ::: "memory");
      __builtin_amdgcn_s_barrier();
    }
  }

  if (OUT_MODE == 2) {
    unsigned short* sc = smem;
    const int wr4 = wr >> 2;
#pragma unroll
    for (int m = 0; m < 4; ++m)
#pragma unroll
      for (int n = 0; n < 4; ++n) {
        int col = wc + n * 16 + r;
        float bv = bias[bcol + col];
        int sl = wr4 + m * 4 + g;                       // local key 0..31
        int pp = ((sl >> 2) & 3) * 8 + ((sl >> 4) & 1) * 4 + (sl & 3);  // sigma
#pragma unroll
        for (int rr = 0; rr < 4; ++rr) {
          int c = (rr * 4 + (pp >> 3)) ^ (col & 7);
          sc[col * 128 + c * 8 + (pp & 7)] = f2bf((acc[m][n][rr] + bv) * scale);
        }
      }
    asm volatile("s_waitcnt lgkmcnt(0)" ::: "memory");
    __builtin_amdgcn_s_barrier();
    unsigned short* VT = (unsigned short*)Outp;
#pragma unroll
    for (int i2 = 0; i2 < 2; ++i2) {
      int q = tid * 2 + i2;
      int col = q >> 2, bb = q & 3;
      int gcol = bcol + col, hh = gcol >> 6, nh = gcol & 63;
      size_t gbase = (((size_t)bb * H + hh) * NH + nh) * SL + (brow >> 2);
#pragma unroll
      for (int j = 0; j < 4; ++j) {
        short8 v = *reinterpret_cast<const short8*>(
            &sc[col * 128 + (((bb * 4 + j) ^ (col & 7)) * 8)]);
        *reinterpret_cast<short8*>(&VT[gbase + j * 8]) = v;
      }
    }
  } else {
#pragma unroll
    for (int m = 0; m < 4; ++m)
#pragma unroll
      for (int n = 0; n < 4; ++n) {
        int gcol = bcol + wc + n * 16 + r;
        float bv = bias[gcol];
#pragma unroll
        for (int rr = 0; rr < 4; ++rr) {
          int grow = brow + wr + m * 16 + g * 4 + rr;
          float val = (acc[m][n][rr] + bv) * scale;
          if (OUT_MODE == 0)
            ((float*)Outp)[(size_t)grow * D + gcol] = val;
          else
            ((unsigned short*)Outp)[(size_t)grow * D + gcol] = f2bf(val);
        }
      }
  }
}

__global__ __launch_bounds__(256, 2) void qkv_gemm(
    const float* __restrict__ x0, const float* __restrict__ x1, const float* __restrict__ x2,
    const unsigned short* __restrict__ wtb,
    const float* __restrict__ b0, const float* __restrict__ b1, const float* __restrict__ b2,
    unsigned short* __restrict__ q_out, unsigned short* __restrict__ k_out,
    unsigned short* __restrict__ vt_out) {
  __shared__ __align__(16) unsigned short smem[2 * 16384];
  int z = blockIdx.z;
  const float* X = z == 0 ? x0 : (z == 1 ? x1 : x2);
  const unsigned short* WT = wtb + (size_t)z * D * D;
  const float* B = z == 0 ? b0 : (z == 1 ? b1 : b2);
  float scale = (z == 0) ? SCALE * LOG2E : 1.0f;
  if (z == 2)
    gemm_bt_body<false, 2>(X, WT, B, vt_out, scale, smem);
  else
    gemm_bt_body<false, 1>(X, WT, B, z == 0 ? q_out : k_out, scale, smem);
}

__global__ __launch_bounds__(256, 2) void gemm_oproj(
    const unsigned short* __restrict__ A, const unsigned short* __restrict__ WT,
    const float* __restrict__ B, float* __restrict__ Outp) {
  __shared__ __align__(16) unsigned short smem[2 * 16384];
  gemm_bt_body<true, 0>(A, WT, B, Outp, 1.0f, smem);
}

// ---------------------------------------------------------------------------
// Flash attention v7: v6 + TRIPLE-buffered staging with counted vmcnt(8)
// (stage kt+2 during phase kt; never drain to 0 mid-loop), single-b128 V
// reads (vtb sigma-permuted by the V-GEMM), no setprio (lockstep blocks =
// m190's null regime). In-lane P->PV kept. O aliases Q.
// ---------------------------------------------------------------------------
__global__ __launch_bounds__(256, 3) void flash_attn(
    const unsigned short* __restrict__ Q, const unsigned short* __restrict__ K,
    const unsigned short* __restrict__ Vt, unsigned short* __restrict__ O) {
  __shared__ __align__(16) unsigned short k_lds[3][64 * 64];
  __shared__ __align__(16) unsigned short v_lds[3][64 * 64];

  const int bid = blockIdx.x;
  const int s = bid >> 5, idx = bid & 31;
  const int grp = idx & 7;              // XCD group
  const int bh = grp * 4 + (idx >> 3);  // 4 (b,h) per XCD group
  const int b = bh >> 3, h = bh & 7;
  const int qt = (s < 8) ? 31 - s : (s < 16) ? s + 8 : (s < 24) ? 31 - s : s - 24;
  const int q0 = qt * 64;

  const int tid = threadIdx.x;
  const int w = tid >> 6, lane = tid & 63;
  const int r = lane & 15, g = lane >> 4;
  const int swz = (r & 7) << 3;         // u16-index XOR (bits 3..5)

  const unsigned short* Qb = Q + (size_t)b * D + h * NH;
  const unsigned short* Kb = K + (size_t)b * D + h * NH;
  const unsigned short* Vb = Vt + ((size_t)(b * H + h) * NH) * SL;
  unsigned short* Ob = O + (size_t)b * D + h * NH;

  auto STAGE = [&](int kt, int bsel) {
    unsigned short* kl = &k_lds[bsel][0];
    unsigned short* vl = &v_lds[bsel][0];
#pragma unroll
    for (int j = 0; j < 2; ++j) {
      int c = j * 256 + tid;
      int row = c >> 3, c8 = (c & 7) ^ (row & 7);
      gl16(&Kb[(size_t)(kt * 64 + row) * (BS * D) + c8 * 8], &kl[c * 8]);
      gl16(&Vb[(size_t)row * SL + kt * 64 + c8 * 8], &vl[c * 8]);
    }
  };

  STAGE(0, 0);
  if (qt >= 1) STAGE(1, 1);

  short8 qf[2];
#pragma unroll
  for (int kk = 0; kk < 2; ++kk)
    qf[kk] = *reinterpret_cast<const short8*>(
        &Qb[(size_t)(q0 + w * 16 + r) * (BS * D) + kk * 32 + g * 8]);

  f32x4 oa[4];
#pragma unroll
  for (int n = 0; n < 4; ++n) oa[n] = f32x4{0.f, 0.f, 0.f, 0.f};
  float mr = -1e30f, lrp = 0.f;   // lrp: per-lane partial denominator

  int bsel = 0;
  for (int kt = 0; kt <= qt; ++kt) {
    // tile kt must be complete; STAGE(kt+1) (8 loads) may stay in flight
    if (kt < qt)
      asm volatile("s_waitcnt vmcnt(8)" ::: "memory");
    else
      asm volatile("s_waitcnt vmcnt(0)" ::: "memory");
    __builtin_amdgcn_s_barrier();
    __builtin_amdgcn_sched_barrier(0);
    if (kt + 2 <= qt) {
      int nb = bsel + 2; if (nb >= 3) nb -= 3;
      STAGE(kt + 2, nb);
    }

    const unsigned short* kl = &k_lds[bsel][0];
    const unsigned short* vl = &v_lds[bsel][0];
    short8 kf[2][4];
#pragma unroll
    for (int kk = 0; kk < 2; ++kk)
#pragma unroll
      for (int n = 0; n < 4; ++n)
        kf[kk][n] = *reinterpret_cast<const short8*>(
            &kl[(n * 16 + r) * 64 + ((kk * 32 + g * 8) ^ swz)]);

    f32x4 sv[4];
#pragma unroll
    for (int n = 0; n < 4; ++n) sv[n] = f32x4{0.f, 0.f, 0.f, 0.f};
#pragma unroll
    for (int kk = 0; kk < 2; ++kk)
#pragma unroll
      for (int n = 0; n < 4; ++n)
        sv[n] = __builtin_amdgcn_mfma_f32_16x16x32_bf16(kf[kk][n], qf[kk], sv[n], 0, 0, 0);

    // V^T fragments: single b128 per (kk,n); vtb is sigma-permuted so the
    // key order matches the in-lane P fragment exactly.
    short8 vt[2][4];
#pragma unroll
    for (int kk = 0; kk < 2; ++kk)
#pragma unroll
      for (int n = 0; n < 4; ++n)
        vt[kk][n] = *reinterpret_cast<const short8*>(
            &vl[(n * 16 + r) * 64 + ((kk * 32 + g * 8) ^ swz)]);

    if (kt == qt) {
      int qrow = q0 + w * 16 + r;
#pragma unroll
      for (int n = 0; n < 4; ++n)
#pragma unroll
        for (int rr = 0; rr < 4; ++rr)
          if (kt * 64 + n * 16 + g * 4 + rr > qrow) sv[n][rr] = -1e30f;
    }

    // in-lane max (tree) -> lazy cross-lane reduce
    float t0 = fmaxf(fmaxf(sv[0][0], sv[0][1]), sv[0][2]);
    float t1 = fmaxf(fmaxf(sv[0][3], sv[1][0]), sv[1][1]);
    float t2 = fmaxf(fmaxf(sv[1][2], sv[1][3]), sv[2][0]);
    float t3 = fmaxf(fmaxf(sv[2][1], sv[2][2]), sv[2][3]);
    float t4 = fmaxf(fmaxf(sv[3][0], sv[3][1]), sv[3][2]);
    float mxl = fmaxf(fmaxf(fmaxf(t0, t1), fmaxf(t2, t3)), fmaxf(t4, sv[3][3]));
    bool need = __any(mxl > mr + 8.f);
    float mold = mr;
    float mnew = mold;
    if (need) {
      float mx = fmaxf(mxl, __shfl_xor(mxl, 16));
      mx = fmaxf(mx, __shfl_xor(mx, 32));
      mnew = fmaxf(mold, mx);
    }
#pragma unroll
    for (int n = 0; n < 4; ++n)
#pragma unroll
      for (int rr = 0; rr < 4; ++rr)
        sv[n][rr] = fast_exp2(sv[n][rr] - mnew);
    float a0 = (sv[0][0] + sv[0][1]) + (sv[0][2] + sv[0][3]);
    float a1 = (sv[1][0] + sv[1][1]) + (sv[1][2] + sv[1][3]);
    float a2 = (sv[2][0] + sv[2][1]) + (sv[2][2] + sv[2][3]);
    float a3 = (sv[3][0] + sv[3][1]) + (sv[3][2] + sv[3][3]);
    float psl = (a0 + a1) + (a2 + a3);
    if (need) {
      float sf = fast_exp2(mold - mnew);
      mr = mnew;
      lrp = lrp * sf + psl;
#pragma unroll
      for (int n = 0; n < 4; ++n) oa[n] *= sf;
    } else {
      lrp += psl;
    }

    // P fragments: purely in-lane under sigma
    short8 pf[2];
#pragma unroll
    for (int kk = 0; kk < 2; ++kk) {
      union { unsigned u[4]; short8 s8; } P;
      P.u[0] = cvt_pk_bf16(sv[2 * kk][0], sv[2 * kk][1]);
      P.u[1] = cvt_pk_bf16(sv[2 * kk][2], sv[2 * kk][3]);
      P.u[2] = cvt_pk_bf16(sv[2 * kk + 1][0], sv[2 * kk + 1][1]);
      P.u[3] = cvt_pk_bf16(sv[2 * kk + 1][2], sv[2 * kk + 1][3]);
      pf[kk] = P.s8;
    }

#pragma unroll
    for (int kk = 0; kk < 2; ++kk)
#pragma unroll
      for (int n = 0; n < 4; ++n)
        oa[n] = __builtin_amdgcn_mfma_f32_16x16x32_bf16(vt[kk][n], pf[kk], oa[n], 0, 0, 0);

    ++bsel; if (bsel >= 3) bsel = 0;
  }

  // finalize: reduce lrp once, normalize, transpose via (now-free) k_lds slice
  __syncthreads();
  {
    unsigned short* pw = &k_lds[0][0] + w * 2048;
    float lr = lrp + __shfl_xor(lrp, 16);
    lr += __shfl_xor(lr, 32);
    float inv = 1.0f / lr;
#pragma unroll
    for (int n = 0; n < 4; ++n) {
      uint2v pk;
      pk.x = cvt_pk_bf16(oa[n][0] * inv, oa[n][1] * inv);
      pk.y = cvt_pk_bf16(oa[n][2] * inv, oa[n][3] * inv);
      *reinterpret_cast<uint2v*>(&pw[r * 64 + ((n * 16 + g * 4) ^ swz)]) = pk;
    }
    asm volatile("s_waitcnt lgkmcnt(0)" ::: "memory");
    __builtin_amdgcn_sched_barrier(0);
#pragma unroll
    for (int i2 = 0; i2 < 2; ++i2) {
      int c = i2 * 64 + lane;
      int row = c >> 3, c8 = c & 7;
      short8 v = *reinterpret_cast<const short8*>(&pw[row * 64 + c8 * 8]);
      *reinterpret_cast<short8*>(
          &Ob[(size_t)(q0 + w * 16 + row) * (BS * D) + ((c8 ^ (row & 7)) * 8)]) = v;
    }
  }
}

// ---------------------------------------------------------------------------
extern "C" void kernel_launch(void* const* d_in, const int* in_sizes, int n_in,
                              void* d_out, int out_size, void* d_ws, size_t ws_size,
                              hipStream_t stream) {
  const float* x  = (const float*)d_in[0];
  const float* kx = (const float*)d_in[1];
  const float* vx = (const float*)d_in[2];
  const float* Wq = (const float*)d_in[3];
  const float* bq = (const float*)d_in[4];
  const float* Wk = (const float*)d_in[5];
  const float* bk = (const float*)d_in[6];
  const float* Wv = (const float*)d_in[7];
  const float* bv = (const float*)d_in[8];
  const float* Wo = (const float*)d_in[9];
  const float* bo = (const float*)d_in[10];

  // workspace (bf16), 26 MB: qb (attn-out aliases) | kb | vtb | wtb (2 MB)
  unsigned short* ws = (unsigned short*)d_ws;
  unsigned short* qb  = ws;
  unsigned short* kb  = ws + (size_t)M_ROWS * D;
  unsigned short* vtb = ws + (size_t)M_ROWS * D * 2;
  unsigned short* wtb = ws + (size_t)M_ROWS * D * 3;

  prep_wt<<<dim3(256), dim3(256), 0, stream>>>(Wq, Wk, Wv, Wo, wtb);
  qkv_gemm<<<dim3(64, 4, 3), dim3(256), 0, stream>>>(x, kx, vx, wtb, bq, bk, bv,
                                                     qb, kb, vtb);
  flash_attn<<<dim3(1024), dim3(256), 0, stream>>>(qb, kb, vtb, qb);
  gemm_oproj<<<dim3(64, 4, 1), dim3(256), 0, stream>>>(qb, wtb + (size_t)3 * D * D,
                                                       bo, (float*)d_out);
}